// Round 8
// baseline (232.566 us; speedup 1.0000x reference)
//
#include <hip/hip_runtime.h>
#include <math.h>

typedef unsigned short u16;
typedef unsigned int   u32;

#define B_   16
#define C_   256
#define HW_  1024
#define N_   16384      // B*H*W rows
#define NE_  8192       // codebook entries
#define K_   256        // feature dim
#define NSPLIT 4
#define CPS  2048       // codes per split
#define NZQ  4194304    // B*C*H*W

typedef _Float16 f16x8 __attribute__((ext_vector_type(8)));
typedef float    f32x16 __attribute__((ext_vector_type(16)));

// output layout: [0, NZQ) = z_q (B,C,H,W); [NZQ] = loss; [NZQ+1, NZQ+1+N_) = indices (as float)

__device__ __forceinline__ u16 f2h(float x) {
    union { _Float16 h; u16 u; } c;
    c.h = (_Float16)x;
    return c.u;
}

// ---------------------------------------------------------------------------
// PRE (fused): blocks [0,4096): transpose z (B,C,HW) -> zf/zh [N_,K_];
//              blocks [4096,4224): codebook GEMM 128x128 tile, 8x8/thread
//              (1 B/FLOP LDS ratio, VALU-balanced). Independent inputs ->
//              memory-bound transpose overlaps compute-bound GEMM.
__global__ __launch_bounds__(256) void k_pre(
        const float* __restrict__ z, const float* __restrict__ f,
        const float* __restrict__ w, float* __restrict__ zf,
        u16* __restrict__ zh, float* __restrict__ cb, u16* __restrict__ cbh) {
    __shared__ float tileT[32][33];
    __shared__ float Fs[16][136];
    __shared__ float Ws[16][136];
    int bid = blockIdx.x;
    int tid = threadIdx.x;

    if (bid < 4096) {
        // ---- transpose part
        int hw0 = (bid & 31) * 32;
        int c0  = ((bid >> 5) & 7) * 32;
        int b   = bid >> 8;
        int tx = tid & 31;        // 0..31
        int ty = tid >> 5;        // 0..7
        #pragma unroll
        for (int i = 0; i < 4; ++i) {
            int c = c0 + ty + i * 8;
            tileT[ty + i * 8][tx] = z[((size_t)b * C_ + c) * HW_ + hw0 + tx];
        }
        __syncthreads();
        #pragma unroll
        for (int i = 0; i < 4; ++i) {
            int hw = hw0 + ty + i * 8;
            size_t o = ((size_t)b * HW_ + hw) * C_ + c0 + tx;
            float v = tileT[tx][ty + i * 8];
            zf[o] = v;
            zh[o] = f2h(v);
        }
        return;
    }

    // ---- GEMM part: cb[n][c] = sum_d f[n][d] * w[c][d]
    int gb = bid - 4096;
    int n0 = (gb & 63) << 7;      // 64 row tiles of 128
    int c0 = (gb >> 6) << 7;      // 2 col tiles of 128
    int tx = tid & 15, ty = tid >> 4;
    int rl = tid >> 1;            // 0..127 staging row
    int kh = (tid & 1) << 3;      // 0 or 8 staging k-half
    float acc[8][8] = {};
    float4 fa = *(const float4*)&f[(size_t)(n0 + rl) * K_ + kh];
    float4 fb = *(const float4*)&f[(size_t)(n0 + rl) * K_ + kh + 4];
    float4 wa = *(const float4*)&w[(size_t)(c0 + rl) * K_ + kh];
    float4 wb = *(const float4*)&w[(size_t)(c0 + rl) * K_ + kh + 4];
    for (int kb = 0; kb < K_; kb += 16) {
        __syncthreads();
        Fs[kh + 0][rl] = fa.x; Fs[kh + 1][rl] = fa.y; Fs[kh + 2][rl] = fa.z; Fs[kh + 3][rl] = fa.w;
        Fs[kh + 4][rl] = fb.x; Fs[kh + 5][rl] = fb.y; Fs[kh + 6][rl] = fb.z; Fs[kh + 7][rl] = fb.w;
        Ws[kh + 0][rl] = wa.x; Ws[kh + 1][rl] = wa.y; Ws[kh + 2][rl] = wa.z; Ws[kh + 3][rl] = wa.w;
        Ws[kh + 4][rl] = wb.x; Ws[kh + 5][rl] = wb.y; Ws[kh + 6][rl] = wb.z; Ws[kh + 7][rl] = wb.w;
        __syncthreads();
        if (kb + 16 < K_) {
            fa = *(const float4*)&f[(size_t)(n0 + rl) * K_ + kb + 16 + kh];
            fb = *(const float4*)&f[(size_t)(n0 + rl) * K_ + kb + 16 + kh + 4];
            wa = *(const float4*)&w[(size_t)(c0 + rl) * K_ + kb + 16 + kh];
            wb = *(const float4*)&w[(size_t)(c0 + rl) * K_ + kb + 16 + kh + 4];
        }
        #pragma unroll
        for (int k = 0; k < 16; ++k) {
            float4 a0 = *(float4*)&Fs[k][ty * 8];
            float4 a1 = *(float4*)&Fs[k][ty * 8 + 4];
            float4 b0 = *(float4*)&Ws[k][tx * 8];
            float4 b1 = *(float4*)&Ws[k][tx * 8 + 4];
            float av[8] = {a0.x, a0.y, a0.z, a0.w, a1.x, a1.y, a1.z, a1.w};
            float bv[8] = {b0.x, b0.y, b0.z, b0.w, b1.x, b1.y, b1.z, b1.w};
            #pragma unroll
            for (int i = 0; i < 8; ++i)
                #pragma unroll
                for (int j = 0; j < 8; ++j)
                    acc[i][j] += av[i] * bv[j];
        }
    }
    #pragma unroll
    for (int i = 0; i < 8; ++i) {
        size_t o = (size_t)(n0 + ty * 8 + i) * K_ + c0 + tx * 8;
        *(float4*)&cb[o]     = make_float4(acc[i][0], acc[i][1], acc[i][2], acc[i][3]);
        *(float4*)&cb[o + 4] = make_float4(acc[i][4], acc[i][5], acc[i][6], acc[i][7]);
        *(ushort4*)&cbh[o]     = make_ushort4(f2h(acc[i][0]), f2h(acc[i][1]),
                                              f2h(acc[i][2]), f2h(acc[i][3]));
        *(ushort4*)&cbh[o + 4] = make_ushort4(f2h(acc[i][4]), f2h(acc[i][5]),
                                              f2h(acc[i][6]), f2h(acc[i][7]));
    }
}

// ---------------------------------------------------------------------------
// B2: c2d[n] = ||cb[n]||^2 exact (fp64, for rescore);
//     c2[n]  = 4096*||cb[n]||^2 + 262144  (pre-scaled for the scan's fixed-
//     point packed score: si = 4096*(score+64); score = c2 - 2 dot, |score|<40)
__global__ void k_c2(const float* __restrict__ cb, float* __restrict__ c2,
                     double* __restrict__ c2d) {
    int row  = blockIdx.x * 4 + (threadIdx.x >> 6);
    int lane = threadIdx.x & 63;
    float4 v = *(const float4*)&cb[(size_t)row * K_ + lane * 4];
    double s = (double)v.x * v.x + (double)v.y * v.y
             + (double)v.z * v.z + (double)v.w * v.w;
    #pragma unroll
    for (int off = 32; off; off >>= 1) s += __shfl_down(s, off, 64);
    if (lane == 0) { c2d[row] = s; c2[row] = (float)(s * 4096.0 + 262144.0); }
}

// ---------------------------------------------------------------------------
// C: fp16 MFMA distance scan (R7 structure, measured 85us). Block 128 codes x
// 128 zrows; wave tile 64x64; z in registers. 4-buffer LDS ring, depth-2
// prefetch, counted vmcnt(8), raw s_barrier. t2i now stores FULL PACKED u32
// (score|idx) — comparable across splits (global fixed-point scale).
__device__ __forceinline__ void ld_lds16(const void* g, void* l) {
    __builtin_amdgcn_global_load_lds((const __attribute__((address_space(1))) void*)g,
                                     (__attribute__((address_space(3))) void*)l, 16, 0, 0);
}

#define INS(M1, M2, U) { u32 t_ = min(M1, U); u32 h_ = max(M1, U); M1 = t_; M2 = min(M2, h_); }

#define SCORE16(ACC, M1, M2, CGBASE, C2B) do {                                    \
    u32 ib_ = (u32)(code0 + (CGBASE));                                            \
    _Pragma("unroll")                                                             \
    for (int h = 0; h < 4; ++h) {                                                 \
        float4 cv = *(const float4*)&(C2B)[(CGBASE) + 8 * h];                     \
        u32 u0 = (((u32)fmaf(-8192.f, (ACC)[4*h+0], cv.x)) << 13) + ib_ + 8*h + 0; \
        u32 u1 = (((u32)fmaf(-8192.f, (ACC)[4*h+1], cv.y)) << 13) + ib_ + 8*h + 1; \
        u32 u2 = (((u32)fmaf(-8192.f, (ACC)[4*h+2], cv.z)) << 13) + ib_ + 8*h + 2; \
        u32 u3 = (((u32)fmaf(-8192.f, (ACC)[4*h+3], cv.w)) << 13) + ib_ + 8*h + 3; \
        INS(M1, M2, u0); INS(M1, M2, u1); INS(M1, M2, u2); INS(M1, M2, u3);       \
    }                                                                             \
} while (0)

#define WAITVM(N) { asm volatile("s_waitcnt vmcnt(" #N ")" ::: "memory"); \
                    __builtin_amdgcn_s_barrier();                          \
                    __builtin_amdgcn_sched_barrier(0); }

__global__ __launch_bounds__(256, 2) void k_scan_mfma(
        const u16* __restrict__ zh, const u16* __restrict__ cbh,
        const float* __restrict__ c2, int* __restrict__ t2i) {
    __shared__ __align__(16) u16 sA[4][8192];    // 4-step ring, 64KB total
    __shared__ __align__(16) float c2s[2048];    // whole split's pre-scaled c2 (8KB)

    int r0    = blockIdx.x * 128;
    int split = blockIdx.y;
    int tid  = threadIdx.x;
    int wave = tid >> 6, lane = tid & 63;
    int l31 = lane & 31, q = lane >> 5;
    int ra = ((wave & 1) << 6) + l31;            // A row base (codes)

    const u16* zp = zh + (size_t)(r0 + ((wave >> 1) << 6) + l31) * K_ + q * 8;
    f16x8 zr0[16], zr1[16];
    #pragma unroll
    for (int t = 0; t < 16; ++t) {
        zr0[t] = *(const f16x8*)&zp[t * 16];
        zr1[t] = *(const f16x8*)&zp[32 * K_ + t * 16];
    }

    size_t ga[4]; u32 la[4];
    #pragma unroll
    for (int it = 0; it < 4; ++it) {
        int S = (it * 4 + wave) * 64 + lane;
        int row = S >> 3, u = S & 7;
        ga[it] = (size_t)row * K_ + (u ^ (row & 7)) * 8;
        la[it] = (u32)(it * 4 + wave) * 512;
    }

    u32 m1a = 0xFFFFFFFFu, m2a = 0xFFFFFFFFu;
    u32 m1b = 0xFFFFFFFFu, m2b = 0xFFFFFFFFu;

    const u16* cb0 = cbh + (size_t)split * CPS * K_;

    auto STAGE = [&](int s) {
        const u16* Ab = cb0 + (size_t)(s >> 2) * (128 * K_) + (s & 3) * 64;
        u16* d = &sA[s & 3][0];
        #pragma unroll
        for (int it = 0; it < 4; ++it) ld_lds16(Ab + ga[it], d + la[it]);
    };

    f32x16 acc0 = (f32x16){}, acc1 = (f32x16){}, acc2 = (f32x16){}, acc3 = (f32x16){};

    auto COMPUTE = [&](int ct, int kb) {
        const u16* sAb = &sA[kb][0];
        __builtin_amdgcn_s_setprio(1);
        #pragma unroll
        for (int ks = 0; ks < 4; ++ks) {
            u32 u8 = (u32)(((ks * 2 + q) ^ (l31 & 7)) * 8);
            f16x8 af0 = *(const f16x8*)&sAb[(u32)ra * 64 + u8];
            f16x8 af1 = *(const f16x8*)&sAb[(u32)ra * 64 + 2048 + u8];
            acc0 = __builtin_amdgcn_mfma_f32_32x32x16_f16(af0, zr0[kb * 4 + ks], acc0, 0, 0, 0);
            acc1 = __builtin_amdgcn_mfma_f32_32x32x16_f16(af1, zr0[kb * 4 + ks], acc1, 0, 0, 0);
            acc2 = __builtin_amdgcn_mfma_f32_32x32x16_f16(af0, zr1[kb * 4 + ks], acc2, 0, 0, 0);
            acc3 = __builtin_amdgcn_mfma_f32_32x32x16_f16(af1, zr1[kb * 4 + ks], acc3, 0, 0, 0);
        }
        __builtin_amdgcn_s_setprio(0);
        if (kb == 3) {
            int code0 = split * CPS + ct * 128;
            const float* C2B = &c2s[ct * 128];
            int cga = ((wave & 1) << 6) + (q << 2);
            int cgb = cga + 32;
            SCORE16(acc0, m1a, m2a, cga, C2B);
            SCORE16(acc1, m1a, m2a, cgb, C2B);
            SCORE16(acc2, m1b, m2b, cga, C2B);
            SCORE16(acc3, m1b, m2b, cgb, C2B);
            acc0 = (f32x16){}; acc1 = (f32x16){}; acc2 = (f32x16){}; acc3 = (f32x16){};
        }
    };

    STAGE(0); STAGE(1);
    ld_lds16(&c2[split * CPS + wave * 512 + lane * 4], &c2s[wave * 512]);
    ld_lds16(&c2[split * CPS + wave * 512 + 256 + lane * 4], &c2s[wave * 512 + 256]);
    asm volatile("s_waitcnt vmcnt(0)" ::: "memory");
    __builtin_amdgcn_s_barrier();
    __builtin_amdgcn_sched_barrier(0);

    for (int ct = 0; ct < 15; ++ct) {
        #pragma unroll
        for (int kb = 0; kb < 4; ++kb) {
            STAGE(ct * 4 + kb + 2);
            WAITVM(8);
            COMPUTE(ct, kb);
        }
    }
    STAGE(62); WAITVM(8); COMPUTE(15, 0);
    STAGE(63); WAITVM(8); COMPUTE(15, 1);
    WAITVM(4);            COMPUTE(15, 2);
    WAITVM(0);            COMPUTE(15, 3);

    {
        u32 o1 = __shfl_xor(m1a, 32, 64), o2 = __shfl_xor(m2a, 32, 64);
        u32 h = max(m1a, o1); m1a = min(m1a, o1); m2a = min(min(m2a, o2), h);
        o1 = __shfl_xor(m1b, 32, 64); o2 = __shfl_xor(m2b, 32, 64);
        h = max(m1b, o1); m1b = min(m1b, o1); m2b = min(min(m2b, o2), h);
    }
    u32* mbuf = (u32*)&sA[0][0];
    if (q == 0) {
        int base = ((wave * 2 + 0) * 32 + l31) * 2;
        mbuf[base] = m1a; mbuf[base + 1] = m2a;
        base = ((wave * 2 + 1) * 32 + l31) * 2;
        mbuf[base] = m1b; mbuf[base + 1] = m2b;
    }
    __syncthreads();
    if (tid < 128) {
        int zr = tid, wp = zr >> 6, zg = (zr >> 5) & 1, l = zr & 31;
        int iA = (((wp * 2 + 0) * 2 + zg) * 32 + l) * 2;
        int iB = (((wp * 2 + 1) * 2 + zg) * 32 + l) * 2;
        u32 a1 = mbuf[iA], a2 = mbuf[iA + 1];
        u32 b1 = mbuf[iB], b2 = mbuf[iB + 1];
        u32 h  = max(a1, b1), f1 = min(a1, b1);
        u32 f2 = min(min(a2, b2), h);
        size_t o = ((size_t)split * N_ + (r0 + zr)) * 2;
        t2i[o] = (int)f1;          // PACKED (score|idx)
        t2i[o + 1] = (int)f2;
    }
}

// ---------------------------------------------------------------------------
// D: windowed fp64 rescore. Packed scores are globally comparable; if the
// 2nd-best packed is >= W above best, best IS the argmin (packed compare ==
// (score, idx) lexicographic) -> zero cb reads. Else rescore only in-window
// candidates (W = 160<<13 = 0.039 L2-units, ~20 sigma of fp16 score error).
// Loss folded in via atomicAdd(float) (out zeroed by harness each launch).
__global__ __launch_bounds__(256) void k_finalize(
        const float* __restrict__ zf, const float* __restrict__ cb,
        const double* __restrict__ c2d, const u32* __restrict__ t2i,
        float* __restrict__ out) {
    __shared__ int   bidx[16];
    __shared__ float wsum[4];
    __shared__ float tile[16][260];
    int n0 = blockIdx.x * 16;
    int tid = threadIdx.x;
    int wv = tid >> 6, lane = tid & 63;
    int h = lane >> 5, l5 = lane & 31;
    const u32 W = 160u << 13;

    for (int rr = 0; rr < 4; ++rr) {
        int n = n0 + wv * 4 + rr;
        u32 pkA[4], pkB[4];
        #pragma unroll
        for (int p = 0; p < 4; ++p) {
            pkA[p] = t2i[((size_t)p * N_ + n) * 2 + 0];
            pkB[p] = t2i[((size_t)p * N_ + n) * 2 + 1];
        }
        u32 b1 = 0xFFFFFFFFu, b2 = 0xFFFFFFFFu;
        #pragma unroll
        for (int p = 0; p < 4; ++p) { INS(b1, b2, pkA[p]); INS(b1, b2, pkB[p]); }

        int bi;
        if (b2 - b1 >= W) {
            bi = (int)(b1 & 0x1FFFu);          // unambiguous: zero cb reads
        } else {
            const float* zp = zf + (size_t)n * K_;
            float4 za = *(const float4*)&zp[l5 * 4];
            float4 zb = *(const float4*)&zp[l5 * 4 + 128];
            double bs = 1e300; bi = 0x7fffffff;
            #pragma unroll
            for (int p = 0; p < 4; ++p) {
                u32 pa = pkA[p], pb = pkB[p];
                if ((pa - b1 < W) || (pb - b1 < W)) {
                    u32 psel = h ? pb : pa;
                    int ci = (int)(psel & 0x1FFFu);
                    bool inw = (psel - b1) < W;
                    float4 ca = *(const float4*)&cb[(size_t)ci * K_ + l5 * 4];
                    float4 cv = *(const float4*)&cb[(size_t)ci * K_ + l5 * 4 + 128];
                    double acc = (double)za.x * ca.x + (double)za.y * ca.y
                               + (double)za.z * ca.z + (double)za.w * ca.w
                               + (double)zb.x * cv.x + (double)zb.y * cv.y
                               + (double)zb.z * cv.z + (double)zb.w * cv.w;
                    #pragma unroll
                    for (int off = 1; off < 32; off <<= 1) acc += __shfl_xor(acc, off, 32);
                    double sc = inw ? (c2d[ci] - 2.0 * acc) : 1e300;
                    double so = __shfl_xor(sc, 32, 64);
                    int    io = __shfl_xor(ci, 32, 64);
                    double s0 = h ? so : sc;  int i0 = h ? io : ci;   // cand A
                    double s1 = h ? sc : so;  int i1 = h ? ci : io;   // cand B
                    if (s0 < bs || (s0 == bs && i0 < bi)) { bs = s0; bi = i0; }
                    if (s1 < bs || (s1 == bs && i1 < bi)) { bs = s1; bi = i1; }
                }
            }
        }
        if (lane == 0) {
            bidx[wv * 4 + rr] = bi;
            out[(size_t)NZQ + 1 + n] = (float)bi;   // indices output
        }
    }
    __syncthreads();

    // phase 2: gather + squared-error partial + stage for transposed write
    float accl = 0.f;
    for (int l = 0; l < 16; ++l) {
        int n = n0 + l;
        int bi = bidx[l];
        float zq = cb[(size_t)bi * K_ + tid];
        float d  = zf[(size_t)n * K_ + tid] - zq;
        accl += d * d;
        tile[l][tid] = zq;
    }
    #pragma unroll
    for (int off = 32; off; off >>= 1) accl += __shfl_down(accl, off, 64);
    if ((tid & 63) == 0) wsum[tid >> 6] = accl;
    __syncthreads();
    if (tid == 0)
        atomicAdd(out + NZQ, (wsum[0] + wsum[1] + wsum[2] + wsum[3]) * (1.25f / (float)NZQ));
    // transposed write: out[(b*C + c)*HW + hw0 + l]
    int b = n0 >> 10, hw0 = n0 & 1023;
    #pragma unroll
    for (int g = 0; g < 4; ++g) {
        float4 v = make_float4(tile[g * 4 + 0][tid], tile[g * 4 + 1][tid],
                               tile[g * 4 + 2][tid], tile[g * 4 + 3][tid]);
        *(float4*)&out[((size_t)b * C_ + tid) * HW_ + hw0 + g * 4] = v;
    }
}

// ---------------------------------------------------------------------------
extern "C" void kernel_launch(void* const* d_in, const int* in_sizes, int n_in,
                              void* d_out, int out_size, void* d_ws, size_t ws_size,
                              hipStream_t stream) {
    const float* z  = (const float*)d_in[0];
    const float* fc = (const float*)d_in[1];
    const float* wt = (const float*)d_in[2];
    float* out = (float*)d_out;

    float* ws = (float*)d_ws;
    const size_t OFF_ZF   = 0;                                   // N*K f
    const size_t OFF_CB   = OFF_ZF + (size_t)N_ * K_;            // NE*K f
    const size_t OFF_C2   = OFF_CB + (size_t)NE_ * K_;           // NE f
    const size_t OFF_C2D  = OFF_C2 + NE_;                        // NE d (2 f each)
    const size_t OFF_T2I  = OFF_C2D + (size_t)NE_ * 2;           // NSPLIT*N*2 i
    const size_t OFF_ZH   = OFF_T2I + (size_t)NSPLIT * N_ * 2;   // fp16 N*K
    const size_t OFF_CBH  = OFF_ZH + (size_t)N_ * K_ / 2;        // fp16 NE*K

    float*  zf   = ws + OFF_ZF;
    float*  cb   = ws + OFF_CB;
    float*  c2   = ws + OFF_C2;
    double* c2d  = (double*)(ws + OFF_C2D);
    int*    t2i  = (int*)(ws + OFF_T2I);
    u16*    zh   = (u16*)(ws + OFF_ZH);
    u16*    cbh  = (u16*)(ws + OFF_CBH);

    k_pre<<<4096 + 128, 256, 0, stream>>>(z, fc, wt, zf, zh, cb, cbh);
    k_c2<<<NE_ / 4, 256, 0, stream>>>(cb, c2, c2d);
    k_scan_mfma<<<dim3(N_ / 128, NSPLIT), 256, 0, stream>>>(zh, cbh, c2, t2i);
    k_finalize<<<N_ / 16, 256, 0, stream>>>(zf, cb, c2d, (const u32*)t2i, out);
}

// Round 9
// 197.977 us; speedup vs baseline: 1.1747x; 1.1747x over previous
//
#include <hip/hip_runtime.h>
#include <math.h>

typedef unsigned short u16;
typedef unsigned int   u32;

#define B_   16
#define C_   256
#define HW_  1024
#define N_   16384      // B*H*W rows
#define NE_  8192       // codebook entries
#define K_   256        // feature dim
#define NSPLIT 4
#define CPS  2048       // codes per split
#define NZQ  4194304    // B*C*H*W

typedef _Float16 f16x8 __attribute__((ext_vector_type(8)));
typedef float    f32x16 __attribute__((ext_vector_type(16)));

// output layout: [0, NZQ) = z_q (B,C,H,W); [NZQ] = loss; [NZQ+1, NZQ+1+N_) = indices (as float)

__device__ __forceinline__ u16 f2h(float x) {
    union { _Float16 h; u16 u; } c;
    c.h = (_Float16)x;
    return c.u;
}

// ---------------------------------------------------------------------------
// A: transpose z (B,C,HW) -> z_flat [N_, K_] fp32 + fp16  (R7 version)
__global__ void k_transpose_z(const float* __restrict__ z, float* __restrict__ zf,
                              u16* __restrict__ zh) {
    __shared__ float tile[32][33];
    int b   = blockIdx.z;
    int hw0 = blockIdx.x * 32;
    int c0  = blockIdx.y * 32;
    int tx = threadIdx.x;   // 0..31
    int ty = threadIdx.y;   // 0..7
    #pragma unroll
    for (int i = 0; i < 4; ++i) {
        int c = c0 + ty + i * 8;
        tile[ty + i * 8][tx] = z[((size_t)b * C_ + c) * HW_ + hw0 + tx];
    }
    __syncthreads();
    #pragma unroll
    for (int i = 0; i < 4; ++i) {
        int hw = hw0 + ty + i * 8;
        size_t o = ((size_t)b * HW_ + hw) * C_ + c0 + tx;
        float v = tile[tx][ty + i * 8];
        zf[o] = v;
        zh[o] = f2h(v);
    }
}

// ---------------------------------------------------------------------------
// B: codebook GEMM (R7 version): 64x64 tile, 512 blocks (2/CU), prefetched.
__global__ __launch_bounds__(256) void k_codebook_gemm(
        const float* __restrict__ f, const float* __restrict__ w,
        float* __restrict__ cb, u16* __restrict__ cbh) {
    __shared__ float Fs[16][68];
    __shared__ float Ws[16][68];
    int n0 = blockIdx.x * 64;
    int c0 = blockIdx.y * 64;
    int tid = threadIdx.x;
    int tx = tid & 15, ty = tid >> 4;
    int nl = tid >> 2;            // 0..63
    int kq = (tid & 3) * 4;       // 0,4,8,12
    float acc[4][4] = {};
    float4 fv = *(const float4*)&f[(size_t)(n0 + nl) * K_ + kq];
    float4 wv = *(const float4*)&w[(size_t)(c0 + nl) * K_ + kq];
    for (int kb = 0; kb < K_; kb += 16) {
        __syncthreads();
        Fs[kq + 0][nl] = fv.x; Fs[kq + 1][nl] = fv.y; Fs[kq + 2][nl] = fv.z; Fs[kq + 3][nl] = fv.w;
        Ws[kq + 0][nl] = wv.x; Ws[kq + 1][nl] = wv.y; Ws[kq + 2][nl] = wv.z; Ws[kq + 3][nl] = wv.w;
        __syncthreads();
        if (kb + 16 < K_) {
            fv = *(const float4*)&f[(size_t)(n0 + nl) * K_ + kb + 16 + kq];
            wv = *(const float4*)&w[(size_t)(c0 + nl) * K_ + kb + 16 + kq];
        }
        #pragma unroll
        for (int k = 0; k < 16; ++k) {
            float4 a = *(float4*)&Fs[k][ty * 4];
            float4 b = *(float4*)&Ws[k][tx * 4];
            float av[4] = {a.x, a.y, a.z, a.w};
            float bv[4] = {b.x, b.y, b.z, b.w};
            #pragma unroll
            for (int i = 0; i < 4; ++i)
                #pragma unroll
                for (int j = 0; j < 4; ++j)
                    acc[i][j] += av[i] * bv[j];
        }
    }
    #pragma unroll
    for (int i = 0; i < 4; ++i) {
        size_t o = (size_t)(n0 + ty * 4 + i) * K_ + c0 + tx * 4;
        *(float4*)&cb[o] = make_float4(acc[i][0], acc[i][1], acc[i][2], acc[i][3]);
        *(ushort4*)&cbh[o] = make_ushort4(f2h(acc[i][0]), f2h(acc[i][1]),
                                          f2h(acc[i][2]), f2h(acc[i][3]));
    }
}

// ---------------------------------------------------------------------------
// B2: c2d[n] = ||cb[n]||^2 exact (fp64); c2[n] = 4096*||cb[n]||^2 + 262144
__global__ void k_c2(const float* __restrict__ cb, float* __restrict__ c2,
                     double* __restrict__ c2d) {
    int row  = blockIdx.x * 4 + (threadIdx.x >> 6);
    int lane = threadIdx.x & 63;
    float4 v = *(const float4*)&cb[(size_t)row * K_ + lane * 4];
    double s = (double)v.x * v.x + (double)v.y * v.y
             + (double)v.z * v.z + (double)v.w * v.w;
    #pragma unroll
    for (int off = 32; off; off >>= 1) s += __shfl_down(s, off, 64);
    if (lane == 0) { c2d[row] = s; c2[row] = (float)(s * 4096.0 + 262144.0); }
}

// ---------------------------------------------------------------------------
// C: fp16 MFMA distance scan (R7 structure, measured 85us). t2i stores FULL
// PACKED u32 (score|idx) — globally comparable fixed-point scale.
__device__ __forceinline__ void ld_lds16(const void* g, void* l) {
    __builtin_amdgcn_global_load_lds((const __attribute__((address_space(1))) void*)g,
                                     (__attribute__((address_space(3))) void*)l, 16, 0, 0);
}

#define INS(M1, M2, U) { u32 t_ = min(M1, U); u32 h_ = max(M1, U); M1 = t_; M2 = min(M2, h_); }

#define SCORE16(ACC, M1, M2, CGBASE, C2B) do {                                    \
    u32 ib_ = (u32)(code0 + (CGBASE));                                            \
    _Pragma("unroll")                                                             \
    for (int h = 0; h < 4; ++h) {                                                 \
        float4 cv = *(const float4*)&(C2B)[(CGBASE) + 8 * h];                     \
        u32 u0 = (((u32)fmaf(-8192.f, (ACC)[4*h+0], cv.x)) << 13) + ib_ + 8*h + 0; \
        u32 u1 = (((u32)fmaf(-8192.f, (ACC)[4*h+1], cv.y)) << 13) + ib_ + 8*h + 1; \
        u32 u2 = (((u32)fmaf(-8192.f, (ACC)[4*h+2], cv.z)) << 13) + ib_ + 8*h + 2; \
        u32 u3 = (((u32)fmaf(-8192.f, (ACC)[4*h+3], cv.w)) << 13) + ib_ + 8*h + 3; \
        INS(M1, M2, u0); INS(M1, M2, u1); INS(M1, M2, u2); INS(M1, M2, u3);       \
    }                                                                             \
} while (0)

#define WAITVM(N) { asm volatile("s_waitcnt vmcnt(" #N ")" ::: "memory"); \
                    __builtin_amdgcn_s_barrier();                          \
                    __builtin_amdgcn_sched_barrier(0); }

__global__ __launch_bounds__(256, 2) void k_scan_mfma(
        const u16* __restrict__ zh, const u16* __restrict__ cbh,
        const float* __restrict__ c2, int* __restrict__ t2i) {
    __shared__ __align__(16) u16 sA[4][8192];    // 4-step ring, 64KB total
    __shared__ __align__(16) float c2s[2048];    // whole split's pre-scaled c2 (8KB)

    int r0    = blockIdx.x * 128;
    int split = blockIdx.y;
    int tid  = threadIdx.x;
    int wave = tid >> 6, lane = tid & 63;
    int l31 = lane & 31, q = lane >> 5;
    int ra = ((wave & 1) << 6) + l31;            // A row base (codes)

    const u16* zp = zh + (size_t)(r0 + ((wave >> 1) << 6) + l31) * K_ + q * 8;
    f16x8 zr0[16], zr1[16];
    #pragma unroll
    for (int t = 0; t < 16; ++t) {
        zr0[t] = *(const f16x8*)&zp[t * 16];
        zr1[t] = *(const f16x8*)&zp[32 * K_ + t * 16];
    }

    size_t ga[4]; u32 la[4];
    #pragma unroll
    for (int it = 0; it < 4; ++it) {
        int S = (it * 4 + wave) * 64 + lane;
        int row = S >> 3, u = S & 7;
        ga[it] = (size_t)row * K_ + (u ^ (row & 7)) * 8;
        la[it] = (u32)(it * 4 + wave) * 512;
    }

    u32 m1a = 0xFFFFFFFFu, m2a = 0xFFFFFFFFu;
    u32 m1b = 0xFFFFFFFFu, m2b = 0xFFFFFFFFu;

    const u16* cb0 = cbh + (size_t)split * CPS * K_;

    auto STAGE = [&](int s) {
        const u16* Ab = cb0 + (size_t)(s >> 2) * (128 * K_) + (s & 3) * 64;
        u16* d = &sA[s & 3][0];
        #pragma unroll
        for (int it = 0; it < 4; ++it) ld_lds16(Ab + ga[it], d + la[it]);
    };

    f32x16 acc0 = (f32x16){}, acc1 = (f32x16){}, acc2 = (f32x16){}, acc3 = (f32x16){};

    auto COMPUTE = [&](int ct, int kb) {
        const u16* sAb = &sA[kb][0];
        __builtin_amdgcn_s_setprio(1);
        #pragma unroll
        for (int ks = 0; ks < 4; ++ks) {
            u32 u8 = (u32)(((ks * 2 + q) ^ (l31 & 7)) * 8);
            f16x8 af0 = *(const f16x8*)&sAb[(u32)ra * 64 + u8];
            f16x8 af1 = *(const f16x8*)&sAb[(u32)ra * 64 + 2048 + u8];
            acc0 = __builtin_amdgcn_mfma_f32_32x32x16_f16(af0, zr0[kb * 4 + ks], acc0, 0, 0, 0);
            acc1 = __builtin_amdgcn_mfma_f32_32x32x16_f16(af1, zr0[kb * 4 + ks], acc1, 0, 0, 0);
            acc2 = __builtin_amdgcn_mfma_f32_32x32x16_f16(af0, zr1[kb * 4 + ks], acc2, 0, 0, 0);
            acc3 = __builtin_amdgcn_mfma_f32_32x32x16_f16(af1, zr1[kb * 4 + ks], acc3, 0, 0, 0);
        }
        __builtin_amdgcn_s_setprio(0);
        if (kb == 3) {
            int code0 = split * CPS + ct * 128;
            const float* C2B = &c2s[ct * 128];
            int cga = ((wave & 1) << 6) + (q << 2);
            int cgb = cga + 32;
            SCORE16(acc0, m1a, m2a, cga, C2B);
            SCORE16(acc1, m1a, m2a, cgb, C2B);
            SCORE16(acc2, m1b, m2b, cga, C2B);
            SCORE16(acc3, m1b, m2b, cgb, C2B);
            acc0 = (f32x16){}; acc1 = (f32x16){}; acc2 = (f32x16){}; acc3 = (f32x16){};
        }
    };

    STAGE(0); STAGE(1);
    ld_lds16(&c2[split * CPS + wave * 512 + lane * 4], &c2s[wave * 512]);
    ld_lds16(&c2[split * CPS + wave * 512 + 256 + lane * 4], &c2s[wave * 512 + 256]);
    asm volatile("s_waitcnt vmcnt(0)" ::: "memory");
    __builtin_amdgcn_s_barrier();
    __builtin_amdgcn_sched_barrier(0);

    for (int ct = 0; ct < 15; ++ct) {
        #pragma unroll
        for (int kb = 0; kb < 4; ++kb) {
            STAGE(ct * 4 + kb + 2);
            WAITVM(8);
            COMPUTE(ct, kb);
        }
    }
    STAGE(62); WAITVM(8); COMPUTE(15, 0);
    STAGE(63); WAITVM(8); COMPUTE(15, 1);
    WAITVM(4);            COMPUTE(15, 2);
    WAITVM(0);            COMPUTE(15, 3);

    {
        u32 o1 = __shfl_xor(m1a, 32, 64), o2 = __shfl_xor(m2a, 32, 64);
        u32 h = max(m1a, o1); m1a = min(m1a, o1); m2a = min(min(m2a, o2), h);
        o1 = __shfl_xor(m1b, 32, 64); o2 = __shfl_xor(m2b, 32, 64);
        h = max(m1b, o1); m1b = min(m1b, o1); m2b = min(min(m2b, o2), h);
    }
    u32* mbuf = (u32*)&sA[0][0];
    if (q == 0) {
        int base = ((wave * 2 + 0) * 32 + l31) * 2;
        mbuf[base] = m1a; mbuf[base + 1] = m2a;
        base = ((wave * 2 + 1) * 32 + l31) * 2;
        mbuf[base] = m1b; mbuf[base + 1] = m2b;
    }
    __syncthreads();
    if (tid < 128) {
        int zr = tid, wp = zr >> 6, zg = (zr >> 5) & 1, l = zr & 31;
        int iA = (((wp * 2 + 0) * 2 + zg) * 32 + l) * 2;
        int iB = (((wp * 2 + 1) * 2 + zg) * 32 + l) * 2;
        u32 a1 = mbuf[iA], a2 = mbuf[iA + 1];
        u32 b1 = mbuf[iB], b2 = mbuf[iB + 1];
        u32 h  = max(a1, b1), f1 = min(a1, b1);
        u32 f2 = min(min(a2, b2), h);
        size_t o = ((size_t)split * N_ + (r0 + zr)) * 2;
        t2i[o] = (int)f1;          // PACKED (score|idx)
        t2i[o + 1] = (int)f2;
    }
}

// ---------------------------------------------------------------------------
// D: fp64 rescore with packed-skip. Packed scores globally comparable; if the
// 2nd-best packed is >= W above best, the best IS the argmin (packed compare
// == (score,idx) lexicographic) -> zero loads. Else: R7's PIPELINED full-8
// rescore (z row in regs, cid/c2d prefetched, cb row p+1 issued before
// compute of p). Loss folded via atomicAdd (out zeroed by harness).
__global__ __launch_bounds__(256) void k_finalize(
        const float* __restrict__ zf, const float* __restrict__ cb,
        const double* __restrict__ c2d, const u32* __restrict__ t2i,
        float* __restrict__ out) {
    __shared__ int   bidx[16];
    __shared__ float wsum[4];
    __shared__ float tile[16][260];
    int n0 = blockIdx.x * 16;
    int tid = threadIdx.x;
    int wv = tid >> 6, lane = tid & 63;
    int h = lane >> 5, l5 = lane & 31;
    const u32 W = 160u << 13;

    for (int rr = 0; rr < 4; ++rr) {
        int n = n0 + wv * 4 + rr;
        u32 pk[4];                       // this lane-half's candidate per split
        u32 b1 = 0xFFFFFFFFu, b2 = 0xFFFFFFFFu;
        #pragma unroll
        for (int p = 0; p < 4; ++p) {
            u32 pa = t2i[((size_t)p * N_ + n) * 2 + 0];
            u32 pb = t2i[((size_t)p * N_ + n) * 2 + 1];
            pk[p] = h ? pb : pa;
            INS(b1, b2, pa); INS(b1, b2, pb);
        }

        int bi;
        if (b2 - b1 >= W) {
            bi = (int)(b1 & 0x1FFFu);    // unambiguous: zero loads
        } else {
            // R7 pipelined full-8 rescore
            const float* zp = zf + (size_t)n * K_;
            float4 za = *(const float4*)&zp[l5 * 4];
            float4 zb = *(const float4*)&zp[l5 * 4 + 128];
            int cid[4];
            #pragma unroll
            for (int p = 0; p < 4; ++p) cid[p] = (int)(pk[p] & 0x1FFFu);
            double c2p[4];
            #pragma unroll
            for (int p = 0; p < 4; ++p) c2p[p] = c2d[cid[p]];
            float4 cva = *(const float4*)&cb[(size_t)cid[0] * K_ + l5 * 4];
            float4 cvb = *(const float4*)&cb[(size_t)cid[0] * K_ + l5 * 4 + 128];

            double bs = 1e300; bi = 0x7fffffff;
            #pragma unroll
            for (int p = 0; p < 4; ++p) {
                float4 ca = cva, cbv = cvb;
                if (p < 3) {
                    cva = *(const float4*)&cb[(size_t)cid[p + 1] * K_ + l5 * 4];
                    cvb = *(const float4*)&cb[(size_t)cid[p + 1] * K_ + l5 * 4 + 128];
                }
                double acc = (double)za.x * ca.x + (double)za.y * ca.y
                           + (double)za.z * ca.z + (double)za.w * ca.w
                           + (double)zb.x * cbv.x + (double)zb.y * cbv.y
                           + (double)zb.z * cbv.z + (double)zb.w * cbv.w;
                #pragma unroll
                for (int off = 1; off < 32; off <<= 1) acc += __shfl_xor(acc, off, 32);
                double sc = c2p[p] - 2.0 * acc;
                int    ci = cid[p];
                double so = __shfl_xor(sc, 32, 64);
                int    io = __shfl_xor(ci, 32, 64);
                double s0 = h ? so : sc;  int i0 = h ? io : ci;   // cand A (first)
                double s1 = h ? sc : so;  int i1 = h ? ci : io;   // cand B (second)
                if (s0 < bs || (s0 == bs && i0 < bi)) { bs = s0; bi = i0; }
                if (s1 < bs || (s1 == bs && i1 < bi)) { bs = s1; bi = i1; }
            }
        }
        if (lane == 0) {
            bidx[wv * 4 + rr] = bi;
            out[(size_t)NZQ + 1 + n] = (float)bi;   // indices output
        }
    }
    __syncthreads();

    // phase 2: gather + squared-error partial + stage for transposed write
    float accl = 0.f;
    for (int l = 0; l < 16; ++l) {
        int n = n0 + l;
        int bi = bidx[l];
        float zq = cb[(size_t)bi * K_ + tid];
        float d  = zf[(size_t)n * K_ + tid] - zq;
        accl += d * d;
        tile[l][tid] = zq;
    }
    #pragma unroll
    for (int off = 32; off; off >>= 1) accl += __shfl_down(accl, off, 64);
    if ((tid & 63) == 0) wsum[tid >> 6] = accl;
    __syncthreads();
    if (tid == 0)
        atomicAdd(out + NZQ, (wsum[0] + wsum[1] + wsum[2] + wsum[3]) * (1.25f / (float)NZQ));
    // transposed write: out[(b*C + c)*HW + hw0 + l]
    int b = n0 >> 10, hw0 = n0 & 1023;
    #pragma unroll
    for (int g = 0; g < 4; ++g) {
        float4 v = make_float4(tile[g * 4 + 0][tid], tile[g * 4 + 1][tid],
                               tile[g * 4 + 2][tid], tile[g * 4 + 3][tid]);
        *(float4*)&out[((size_t)b * C_ + tid) * HW_ + hw0 + g * 4] = v;
    }
}

// ---------------------------------------------------------------------------
extern "C" void kernel_launch(void* const* d_in, const int* in_sizes, int n_in,
                              void* d_out, int out_size, void* d_ws, size_t ws_size,
                              hipStream_t stream) {
    const float* z  = (const float*)d_in[0];
    const float* fc = (const float*)d_in[1];
    const float* wt = (const float*)d_in[2];
    float* out = (float*)d_out;

    float* ws = (float*)d_ws;
    const size_t OFF_ZF   = 0;                                   // N*K f
    const size_t OFF_CB   = OFF_ZF + (size_t)N_ * K_;            // NE*K f
    const size_t OFF_C2   = OFF_CB + (size_t)NE_ * K_;           // NE f
    const size_t OFF_C2D  = OFF_C2 + NE_;                        // NE d (2 f each)
    const size_t OFF_T2I  = OFF_C2D + (size_t)NE_ * 2;           // NSPLIT*N*2 i
    const size_t OFF_ZH   = OFF_T2I + (size_t)NSPLIT * N_ * 2;   // fp16 N*K
    const size_t OFF_CBH  = OFF_ZH + (size_t)N_ * K_ / 2;        // fp16 NE*K

    float*  zf   = ws + OFF_ZF;
    float*  cb   = ws + OFF_CB;
    float*  c2   = ws + OFF_C2;
    double* c2d  = (double*)(ws + OFF_C2D);
    int*    t2i  = (int*)(ws + OFF_T2I);
    u16*    zh   = (u16*)(ws + OFF_ZH);
    u16*    cbh  = (u16*)(ws + OFF_CBH);

    k_transpose_z<<<dim3(HW_ / 32, C_ / 32, B_), dim3(32, 8), 0, stream>>>(z, zf, zh);
    k_codebook_gemm<<<dim3(NE_ / 64, K_ / 64), 256, 0, stream>>>(fc, wt, cb, cbh);
    k_c2<<<NE_ / 4, 256, 0, stream>>>(cb, c2, c2d);
    k_scan_mfma<<<dim3(N_ / 128, NSPLIT), 256, 0, stream>>>(zh, cbh, c2, t2i);
    k_finalize<<<N_ / 16, 256, 0, stream>>>(zf, cb, c2d, (const u32*)t2i, out);
}

// Round 10
// 197.424 us; speedup vs baseline: 1.1780x; 1.0028x over previous
//
#include <hip/hip_runtime.h>
#include <math.h>

typedef unsigned short u16;
typedef unsigned int   u32;

#define B_   16
#define C_   256
#define HW_  1024
#define N_   16384      // B*H*W rows
#define NE_  8192       // codebook entries
#define K_   256        // feature dim
#define NSPLIT 4
#define CPS  2048       // codes per split
#define NZQ  4194304    // B*C*H*W

typedef _Float16 f16x8 __attribute__((ext_vector_type(8)));
typedef float    f32x16 __attribute__((ext_vector_type(16)));

// output layout: [0, NZQ) = z_q (B,C,H,W); [NZQ] = loss; [NZQ+1, NZQ+1+N_) = indices (as float)

__device__ __forceinline__ u16 f2h(float x) {
    union { _Float16 h; u16 u; } c;
    c.h = (_Float16)x;
    return c.u;
}

// ---------------------------------------------------------------------------
// PRE (fused, gemm-FIRST): blocks [0,512): codebook GEMM 64x64 (R7's measured
// config, 2/CU) + fp64 row-norm partials into c2part[row][4] (deterministic,
// no atomics); blocks [512,4608): transpose z -> zf/zh. Compute-bound GEMM
// dispatched first, memory-bound transpose backfills -> overlap.
__global__ __launch_bounds__(256) void k_pre(
        const float* __restrict__ z, const float* __restrict__ f,
        const float* __restrict__ w, float* __restrict__ zf,
        u16* __restrict__ zh, float* __restrict__ cb, u16* __restrict__ cbh,
        double* __restrict__ c2part) {
    __shared__ float tileT[32][33];
    __shared__ float Fs[16][68];
    __shared__ float Ws[16][68];
    int bid = blockIdx.x;
    int tid = threadIdx.x;

    if (bid >= 512) {
        // ---- transpose part (R7 version, re-indexed)
        int b2  = bid - 512;
        int hw0 = (b2 & 31) * 32;
        int c0  = ((b2 >> 5) & 7) * 32;
        int b   = b2 >> 8;
        int tx = tid & 31;        // 0..31
        int ty = tid >> 5;        // 0..7
        #pragma unroll
        for (int i = 0; i < 4; ++i) {
            int c = c0 + ty + i * 8;
            tileT[ty + i * 8][tx] = z[((size_t)b * C_ + c) * HW_ + hw0 + tx];
        }
        __syncthreads();
        #pragma unroll
        for (int i = 0; i < 4; ++i) {
            int hw = hw0 + ty + i * 8;
            size_t o = ((size_t)b * HW_ + hw) * C_ + c0 + tx;
            float v = tileT[tx][ty + i * 8];
            zf[o] = v;
            zh[o] = f2h(v);
        }
        return;
    }

    // ---- GEMM part (R7 body): cb[n][c] = sum_d f[n][d] * w[c][d]
    int n0 = (bid & 127) * 64;
    int c0 = (bid >> 7) * 64;
    int tx = tid & 15, ty = tid >> 4;
    int nl = tid >> 2;            // 0..63
    int kq = (tid & 3) * 4;       // 0,4,8,12
    float acc[4][4] = {};
    float4 fv = *(const float4*)&f[(size_t)(n0 + nl) * K_ + kq];
    float4 wv = *(const float4*)&w[(size_t)(c0 + nl) * K_ + kq];
    for (int kb = 0; kb < K_; kb += 16) {
        __syncthreads();
        Fs[kq + 0][nl] = fv.x; Fs[kq + 1][nl] = fv.y; Fs[kq + 2][nl] = fv.z; Fs[kq + 3][nl] = fv.w;
        Ws[kq + 0][nl] = wv.x; Ws[kq + 1][nl] = wv.y; Ws[kq + 2][nl] = wv.z; Ws[kq + 3][nl] = wv.w;
        __syncthreads();
        if (kb + 16 < K_) {
            fv = *(const float4*)&f[(size_t)(n0 + nl) * K_ + kb + 16 + kq];
            wv = *(const float4*)&w[(size_t)(c0 + nl) * K_ + kb + 16 + kq];
        }
        #pragma unroll
        for (int k = 0; k < 16; ++k) {
            float4 a = *(float4*)&Fs[k][ty * 4];
            float4 b = *(float4*)&Ws[k][tx * 4];
            float av[4] = {a.x, a.y, a.z, a.w};
            float bv[4] = {b.x, b.y, b.z, b.w};
            #pragma unroll
            for (int i = 0; i < 4; ++i)
                #pragma unroll
                for (int j = 0; j < 4; ++j)
                    acc[i][j] += av[i] * bv[j];
        }
    }
    #pragma unroll
    for (int i = 0; i < 4; ++i) {
        size_t o = (size_t)(n0 + ty * 4 + i) * K_ + c0 + tx * 4;
        *(float4*)&cb[o] = make_float4(acc[i][0], acc[i][1], acc[i][2], acc[i][3]);
        *(ushort4*)&cbh[o] = make_ushort4(f2h(acc[i][0]), f2h(acc[i][1]),
                                          f2h(acc[i][2]), f2h(acc[i][3]));
        // fp64 row-norm partial over this block's 64-col slice
        double ps = (double)acc[i][0] * acc[i][0] + (double)acc[i][1] * acc[i][1]
                  + (double)acc[i][2] * acc[i][2] + (double)acc[i][3] * acc[i][3];
        #pragma unroll
        for (int off = 8; off; off >>= 1) ps += __shfl_down(ps, off, 16);
        if (tx == 0) c2part[(size_t)(n0 + ty * 4 + i) * 4 + (c0 >> 6)] = ps;
    }
}

// ---------------------------------------------------------------------------
// C: fp16 MFMA distance scan (R9 structure, measured 86us). Prologue now
// derives c2s from c2part (sum 4 fp64 partials, scale — identical formula to
// old k_c2) and blockIdx.x==0 materializes c2d for finalize (disjoint writes).
// t2i stores FULL PACKED u32 (score|idx), globally comparable.
__device__ __forceinline__ void ld_lds16(const void* g, void* l) {
    __builtin_amdgcn_global_load_lds((const __attribute__((address_space(1))) void*)g,
                                     (__attribute__((address_space(3))) void*)l, 16, 0, 0);
}

#define INS(M1, M2, U) { u32 t_ = min(M1, U); u32 h_ = max(M1, U); M1 = t_; M2 = min(M2, h_); }

#define SCORE16(ACC, M1, M2, CGBASE, C2B) do {                                    \
    u32 ib_ = (u32)(code0 + (CGBASE));                                            \
    _Pragma("unroll")                                                             \
    for (int h = 0; h < 4; ++h) {                                                 \
        float4 cv = *(const float4*)&(C2B)[(CGBASE) + 8 * h];                     \
        u32 u0 = (((u32)fmaf(-8192.f, (ACC)[4*h+0], cv.x)) << 13) + ib_ + 8*h + 0; \
        u32 u1 = (((u32)fmaf(-8192.f, (ACC)[4*h+1], cv.y)) << 13) + ib_ + 8*h + 1; \
        u32 u2 = (((u32)fmaf(-8192.f, (ACC)[4*h+2], cv.z)) << 13) + ib_ + 8*h + 2; \
        u32 u3 = (((u32)fmaf(-8192.f, (ACC)[4*h+3], cv.w)) << 13) + ib_ + 8*h + 3; \
        INS(M1, M2, u0); INS(M1, M2, u1); INS(M1, M2, u2); INS(M1, M2, u3);       \
    }                                                                             \
} while (0)

#define WAITVM(N) { asm volatile("s_waitcnt vmcnt(" #N ")" ::: "memory"); \
                    __builtin_amdgcn_s_barrier();                          \
                    __builtin_amdgcn_sched_barrier(0); }

__global__ __launch_bounds__(256, 2) void k_scan_mfma(
        const u16* __restrict__ zh, const u16* __restrict__ cbh,
        const double* __restrict__ c2part, double* __restrict__ c2d,
        int* __restrict__ t2i) {
    __shared__ __align__(16) u16 sA[4][8192];    // 4-step ring, 64KB total
    __shared__ __align__(16) float c2s[2048];    // whole split's pre-scaled c2 (8KB)

    int r0    = blockIdx.x * 128;
    int split = blockIdx.y;
    int tid  = threadIdx.x;
    int wave = tid >> 6, lane = tid & 63;
    int l31 = lane & 31, q = lane >> 5;
    int ra = ((wave & 1) << 6) + l31;            // A row base (codes)

    const u16* zp = zh + (size_t)(r0 + ((wave >> 1) << 6) + l31) * K_ + q * 8;
    f16x8 zr0[16], zr1[16];
    #pragma unroll
    for (int t = 0; t < 16; ++t) {
        zr0[t] = *(const f16x8*)&zp[t * 16];
        zr1[t] = *(const f16x8*)&zp[32 * K_ + t * 16];
    }

    size_t ga[4]; u32 la[4];
    #pragma unroll
    for (int it = 0; it < 4; ++it) {
        int S = (it * 4 + wave) * 64 + lane;
        int row = S >> 3, u = S & 7;
        ga[it] = (size_t)row * K_ + (u ^ (row & 7)) * 8;
        la[it] = (u32)(it * 4 + wave) * 512;
    }

    u32 m1a = 0xFFFFFFFFu, m2a = 0xFFFFFFFFu;
    u32 m1b = 0xFFFFFFFFu, m2b = 0xFFFFFFFFu;

    const u16* cb0 = cbh + (size_t)split * CPS * K_;

    auto STAGE = [&](int s) {
        const u16* Ab = cb0 + (size_t)(s >> 2) * (128 * K_) + (s & 3) * 64;
        u16* d = &sA[s & 3][0];
        #pragma unroll
        for (int it = 0; it < 4; ++it) ld_lds16(Ab + ga[it], d + la[it]);
    };

    f32x16 acc0 = (f32x16){}, acc1 = (f32x16){}, acc2 = (f32x16){}, acc3 = (f32x16){};

    auto COMPUTE = [&](int ct, int kb) {
        const u16* sAb = &sA[kb][0];
        __builtin_amdgcn_s_setprio(1);
        #pragma unroll
        for (int ks = 0; ks < 4; ++ks) {
            u32 u8 = (u32)(((ks * 2 + q) ^ (l31 & 7)) * 8);
            f16x8 af0 = *(const f16x8*)&sAb[(u32)ra * 64 + u8];
            f16x8 af1 = *(const f16x8*)&sAb[(u32)ra * 64 + 2048 + u8];
            acc0 = __builtin_amdgcn_mfma_f32_32x32x16_f16(af0, zr0[kb * 4 + ks], acc0, 0, 0, 0);
            acc1 = __builtin_amdgcn_mfma_f32_32x32x16_f16(af1, zr0[kb * 4 + ks], acc1, 0, 0, 0);
            acc2 = __builtin_amdgcn_mfma_f32_32x32x16_f16(af0, zr1[kb * 4 + ks], acc2, 0, 0, 0);
            acc3 = __builtin_amdgcn_mfma_f32_32x32x16_f16(af1, zr1[kb * 4 + ks], acc3, 0, 0, 0);
        }
        __builtin_amdgcn_s_setprio(0);
        if (kb == 3) {
            int code0 = split * CPS + ct * 128;
            const float* C2B = &c2s[ct * 128];
            int cga = ((wave & 1) << 6) + (q << 2);
            int cgb = cga + 32;
            SCORE16(acc0, m1a, m2a, cga, C2B);
            SCORE16(acc1, m1a, m2a, cgb, C2B);
            SCORE16(acc2, m1b, m2b, cga, C2B);
            SCORE16(acc3, m1b, m2b, cgb, C2B);
            acc0 = (f32x16){}; acc1 = (f32x16){}; acc2 = (f32x16){}; acc3 = (f32x16){};
        }
    };

    // prologue: c2s from c2part (8 rows/thread) + c2d materialization (block x==0);
    // stage steps 0,1; one full drain via __syncthreads (covers LDS writes + loads)
    {
        const double* cp = c2part + (size_t)split * CPS * 4;
        #pragma unroll
        for (int r = 0; r < 8; ++r) {
            int row = tid * 8 + r;
            const double* pr = cp + (size_t)row * 4;
            double s = (pr[0] + pr[1]) + (pr[2] + pr[3]);
            c2s[row] = (float)(s * 4096.0 + 262144.0);
            if (blockIdx.x == 0) c2d[split * CPS + row] = s;
        }
    }
    STAGE(0); STAGE(1);
    __syncthreads();
    __builtin_amdgcn_sched_barrier(0);

    for (int ct = 0; ct < 15; ++ct) {
        #pragma unroll
        for (int kb = 0; kb < 4; ++kb) {
            STAGE(ct * 4 + kb + 2);
            WAITVM(8);
            COMPUTE(ct, kb);
        }
    }
    STAGE(62); WAITVM(8); COMPUTE(15, 0);
    STAGE(63); WAITVM(8); COMPUTE(15, 1);
    WAITVM(4);            COMPUTE(15, 2);
    WAITVM(0);            COMPUTE(15, 3);

    {
        u32 o1 = __shfl_xor(m1a, 32, 64), o2 = __shfl_xor(m2a, 32, 64);
        u32 h = max(m1a, o1); m1a = min(m1a, o1); m2a = min(min(m2a, o2), h);
        o1 = __shfl_xor(m1b, 32, 64); o2 = __shfl_xor(m2b, 32, 64);
        h = max(m1b, o1); m1b = min(m1b, o1); m2b = min(min(m2b, o2), h);
    }
    u32* mbuf = (u32*)&sA[0][0];
    if (q == 0) {
        int base = ((wave * 2 + 0) * 32 + l31) * 2;
        mbuf[base] = m1a; mbuf[base + 1] = m2a;
        base = ((wave * 2 + 1) * 32 + l31) * 2;
        mbuf[base] = m1b; mbuf[base + 1] = m2b;
    }
    __syncthreads();
    if (tid < 128) {
        int zr = tid, wp = zr >> 6, zg = (zr >> 5) & 1, l = zr & 31;
        int iA = (((wp * 2 + 0) * 2 + zg) * 32 + l) * 2;
        int iB = (((wp * 2 + 1) * 2 + zg) * 32 + l) * 2;
        u32 a1 = mbuf[iA], a2 = mbuf[iA + 1];
        u32 b1 = mbuf[iB], b2 = mbuf[iB + 1];
        u32 h  = max(a1, b1), f1 = min(a1, b1);
        u32 f2 = min(min(a2, b2), h);
        size_t o = ((size_t)split * N_ + (r0 + zr)) * 2;
        t2i[o] = (int)f1;          // PACKED (score|idx)
        t2i[o + 1] = (int)f2;
    }
}

// ---------------------------------------------------------------------------
// D: fp64 rescore with packed-skip (R9 version, measured good). If 2nd-best
// packed >= W above best, best IS the argmin -> zero loads. Else R7 pipelined
// full-8 rescore. Loss folded via atomicAdd (out zeroed by harness).
__global__ __launch_bounds__(256) void k_finalize(
        const float* __restrict__ zf, const float* __restrict__ cb,
        const double* __restrict__ c2d, const u32* __restrict__ t2i,
        float* __restrict__ out) {
    __shared__ int   bidx[16];
    __shared__ float wsum[4];
    __shared__ float tile[16][260];
    int n0 = blockIdx.x * 16;
    int tid = threadIdx.x;
    int wv = tid >> 6, lane = tid & 63;
    int h = lane >> 5, l5 = lane & 31;
    const u32 W = 160u << 13;

    for (int rr = 0; rr < 4; ++rr) {
        int n = n0 + wv * 4 + rr;
        u32 pk[4];                       // this lane-half's candidate per split
        u32 b1 = 0xFFFFFFFFu, b2 = 0xFFFFFFFFu;
        #pragma unroll
        for (int p = 0; p < 4; ++p) {
            u32 pa = t2i[((size_t)p * N_ + n) * 2 + 0];
            u32 pb = t2i[((size_t)p * N_ + n) * 2 + 1];
            pk[p] = h ? pb : pa;
            INS(b1, b2, pa); INS(b1, b2, pb);
        }

        int bi;
        if (b2 - b1 >= W) {
            bi = (int)(b1 & 0x1FFFu);    // unambiguous: zero loads
        } else {
            // R7 pipelined full-8 rescore
            const float* zp = zf + (size_t)n * K_;
            float4 za = *(const float4*)&zp[l5 * 4];
            float4 zb = *(const float4*)&zp[l5 * 4 + 128];
            int cid[4];
            #pragma unroll
            for (int p = 0; p < 4; ++p) cid[p] = (int)(pk[p] & 0x1FFFu);
            double c2p[4];
            #pragma unroll
            for (int p = 0; p < 4; ++p) c2p[p] = c2d[cid[p]];
            float4 cva = *(const float4*)&cb[(size_t)cid[0] * K_ + l5 * 4];
            float4 cvb = *(const float4*)&cb[(size_t)cid[0] * K_ + l5 * 4 + 128];

            double bs = 1e300; bi = 0x7fffffff;
            #pragma unroll
            for (int p = 0; p < 4; ++p) {
                float4 ca = cva, cbv = cvb;
                if (p < 3) {
                    cva = *(const float4*)&cb[(size_t)cid[p + 1] * K_ + l5 * 4];
                    cvb = *(const float4*)&cb[(size_t)cid[p + 1] * K_ + l5 * 4 + 128];
                }
                double acc = (double)za.x * ca.x + (double)za.y * ca.y
                           + (double)za.z * ca.z + (double)za.w * ca.w
                           + (double)zb.x * cbv.x + (double)zb.y * cbv.y
                           + (double)zb.z * cbv.z + (double)zb.w * cbv.w;
                #pragma unroll
                for (int off = 1; off < 32; off <<= 1) acc += __shfl_xor(acc, off, 32);
                double sc = c2p[p] - 2.0 * acc;
                int    ci = cid[p];
                double so = __shfl_xor(sc, 32, 64);
                int    io = __shfl_xor(ci, 32, 64);
                double s0 = h ? so : sc;  int i0 = h ? io : ci;
                double s1 = h ? sc : so;  int i1 = h ? ci : io;
                if (s0 < bs || (s0 == bs && i0 < bi)) { bs = s0; bi = i0; }
                if (s1 < bs || (s1 == bs && i1 < bi)) { bs = s1; bi = i1; }
            }
        }
        if (lane == 0) {
            bidx[wv * 4 + rr] = bi;
            out[(size_t)NZQ + 1 + n] = (float)bi;   // indices output
        }
    }
    __syncthreads();

    // phase 2: gather + squared-error partial + stage for transposed write
    float accl = 0.f;
    for (int l = 0; l < 16; ++l) {
        int n = n0 + l;
        int bi = bidx[l];
        float zq = cb[(size_t)bi * K_ + tid];
        float d  = zf[(size_t)n * K_ + tid] - zq;
        accl += d * d;
        tile[l][tid] = zq;
    }
    #pragma unroll
    for (int off = 32; off; off >>= 1) accl += __shfl_down(accl, off, 64);
    if ((tid & 63) == 0) wsum[tid >> 6] = accl;
    __syncthreads();
    if (tid == 0)
        atomicAdd(out + NZQ, (wsum[0] + wsum[1] + wsum[2] + wsum[3]) * (1.25f / (float)NZQ));
    // transposed write: out[(b*C + c)*HW + hw0 + l]
    int b = n0 >> 10, hw0 = n0 & 1023;
    #pragma unroll
    for (int g = 0; g < 4; ++g) {
        float4 v = make_float4(tile[g * 4 + 0][tid], tile[g * 4 + 1][tid],
                               tile[g * 4 + 2][tid], tile[g * 4 + 3][tid]);
        *(float4*)&out[((size_t)b * C_ + tid) * HW_ + hw0 + g * 4] = v;
    }
}

// ---------------------------------------------------------------------------
extern "C" void kernel_launch(void* const* d_in, const int* in_sizes, int n_in,
                              void* d_out, int out_size, void* d_ws, size_t ws_size,
                              hipStream_t stream) {
    const float* z  = (const float*)d_in[0];
    const float* fc = (const float*)d_in[1];
    const float* wt = (const float*)d_in[2];
    float* out = (float*)d_out;

    float* ws = (float*)d_ws;
    const size_t OFF_ZF   = 0;                                   // N*K f
    const size_t OFF_CB   = OFF_ZF + (size_t)N_ * K_;            // NE*K f
    const size_t OFF_C2P  = OFF_CB + (size_t)NE_ * K_;           // NE*4 d (8 f each)
    const size_t OFF_C2D  = OFF_C2P + (size_t)NE_ * 8;           // NE d (2 f each)
    const size_t OFF_T2I  = OFF_C2D + (size_t)NE_ * 2;           // NSPLIT*N*2 i
    const size_t OFF_ZH   = OFF_T2I + (size_t)NSPLIT * N_ * 2;   // fp16 N*K
    const size_t OFF_CBH  = OFF_ZH + (size_t)N_ * K_ / 2;        // fp16 NE*K

    float*  zf     = ws + OFF_ZF;
    float*  cb     = ws + OFF_CB;
    double* c2part = (double*)(ws + OFF_C2P);
    double* c2d    = (double*)(ws + OFF_C2D);
    int*    t2i    = (int*)(ws + OFF_T2I);
    u16*    zh     = (u16*)(ws + OFF_ZH);
    u16*    cbh    = (u16*)(ws + OFF_CBH);

    k_pre<<<4608, 256, 0, stream>>>(z, fc, wt, zf, zh, cb, cbh, c2part);
    k_scan_mfma<<<dim3(N_ / 128, NSPLIT), 256, 0, stream>>>(zh, cbh, c2part, c2d, t2i);
    k_finalize<<<N_ / 16, 256, 0, stream>>>(zf, cb, c2d, (const u32*)t2i, out);
}

// Round 11
// 195.233 us; speedup vs baseline: 1.1912x; 1.0112x over previous
//
#include <hip/hip_runtime.h>
#include <math.h>

typedef unsigned short u16;
typedef unsigned int   u32;

#define B_   16
#define C_   256
#define HW_  1024
#define N_   16384      // B*H*W rows
#define NE_  8192       // codebook entries
#define K_   256        // feature dim
#define NSPLIT 4
#define CPS  2048       // codes per split
#define NZQ  4194304    // B*C*H*W

typedef _Float16 f16x8 __attribute__((ext_vector_type(8)));
typedef float    f32x16 __attribute__((ext_vector_type(16)));

// output layout: [0, NZQ) = z_q (B,C,H,W); [NZQ] = loss; [NZQ+1, NZQ+1+N_) = indices (as float)

__device__ __forceinline__ u16 f2h(float x) {
    union { _Float16 h; u16 u; } c;
    c.h = (_Float16)x;
    return c.u;
}
__device__ __forceinline__ float h2f(u16 u) {
    union { _Float16 h; u16 u; } c;
    c.u = u;
    return (float)c.h;
}

// ---------------------------------------------------------------------------
// PRE (fused): blocks [0,128): codebook GEMM via fp16 hi/lo split MFMA
//   (cb = fh*wh + fh*wl + fl*wh; lo*lo ~2^-24 dropped). 128x128 tile, K-step
//   32, stride-80B LDS rows (bank-spread), wave tile 64x64, 12 MFMA/k-slice.
//   Epilogue: cb fp32, cbh fp16, c2part fp64 chunk norms (same formats).
// blocks [128, 4224): transpose z -> zf/zh (R10 version).
__global__ __launch_bounds__(256) void k_pre(
        const float* __restrict__ z, const float* __restrict__ f,
        const float* __restrict__ w, float* __restrict__ zf,
        u16* __restrict__ zh, float* __restrict__ cb, u16* __restrict__ cbh,
        double* __restrict__ c2part) {
    __shared__ float tileT[32][33];
    __shared__ __align__(16) u16 sF[2][128][40];   // [hi/lo][row][32 d + 8 pad]
    __shared__ __align__(16) u16 sW[2][128][40];
    int bid = blockIdx.x;
    int tid = threadIdx.x;

    if (bid >= 128) {
        // ---- transpose part
        int b2  = bid - 128;
        int hw0 = (b2 & 31) * 32;
        int c0t = ((b2 >> 5) & 7) * 32;
        int b   = b2 >> 8;
        int tx = tid & 31;        // 0..31
        int ty = tid >> 5;        // 0..7
        #pragma unroll
        for (int i = 0; i < 4; ++i) {
            int c = c0t + ty + i * 8;
            tileT[ty + i * 8][tx] = z[((size_t)b * C_ + c) * HW_ + hw0 + tx];
        }
        __syncthreads();
        #pragma unroll
        for (int i = 0; i < 4; ++i) {
            int hw = hw0 + ty + i * 8;
            size_t o = ((size_t)b * HW_ + hw) * C_ + c0t + tx;
            float v = tileT[tx][ty + i * 8];
            zf[o] = v;
            zh[o] = f2h(v);
        }
        return;
    }

    // ---- MFMA hi/lo GEMM: cb[n][c] = sum_d f[n][d] * w[c][d]
    int n0 = (bid & 63) * 128;
    int c0 = (bid >> 6) * 128;
    int wave = tid >> 6, lane = tid & 63;
    int l31 = lane & 31, q = lane >> 5;
    int wn = wave & 1, wc = wave >> 1;
    int rl = tid >> 1;            // 0..127 staging row
    int dh = (tid & 1) * 16;      // d-offset within the 32-wide K-step

    f32x16 acc00 = (f32x16){}, acc01 = (f32x16){}, acc10 = (f32x16){}, acc11 = (f32x16){};

    // prefetch step-0 staging data
    float fr[16], wr[16];
    {
        const float* fp = &f[(size_t)(n0 + rl) * K_ + dh];
        const float* wp = &w[(size_t)(c0 + rl) * K_ + dh];
        #pragma unroll
        for (int g = 0; g < 4; ++g) {
            *(float4*)&fr[g * 4] = *(const float4*)&fp[g * 4];
            *(float4*)&wr[g * 4] = *(const float4*)&wp[g * 4];
        }
    }

    for (int s = 0; s < 8; ++s) {
        __syncthreads();   // previous compute done before overwrite
        // convert + write hi/lo to LDS (b128 stores)
        {
            u16 fh[16], fl[16], wh[16], wl[16];
            #pragma unroll
            for (int j = 0; j < 16; ++j) {
                u16 h = f2h(fr[j]); fh[j] = h; fl[j] = f2h(fr[j] - h2f(h));
                h = f2h(wr[j]);     wh[j] = h; wl[j] = f2h(wr[j] - h2f(h));
            }
            #pragma unroll
            for (int g = 0; g < 2; ++g) {
                *(f16x8*)&sF[0][rl][dh + g * 8] = *(f16x8*)&fh[g * 8];
                *(f16x8*)&sF[1][rl][dh + g * 8] = *(f16x8*)&fl[g * 8];
                *(f16x8*)&sW[0][rl][dh + g * 8] = *(f16x8*)&wh[g * 8];
                *(f16x8*)&sW[1][rl][dh + g * 8] = *(f16x8*)&wl[g * 8];
            }
        }
        __syncthreads();
        // prefetch next step (overlaps MFMA below)
        if (s < 7) {
            const float* fp = &f[(size_t)(n0 + rl) * K_ + (s + 1) * 32 + dh];
            const float* wp = &w[(size_t)(c0 + rl) * K_ + (s + 1) * 32 + dh];
            #pragma unroll
            for (int g = 0; g < 4; ++g) {
                *(float4*)&fr[g * 4] = *(const float4*)&fp[g * 4];
                *(float4*)&wr[g * 4] = *(const float4*)&wp[g * 4];
            }
        }
        // compute: 2 k-slices x 4 tiles x 3 products
        #pragma unroll
        for (int ks = 0; ks < 2; ++ks) {
            u32 uo = (u32)(ks * 2 + q) * 8;
            int rA = wn * 64 + l31, rB = wc * 64 + l31;
            f16x8 ah0 = *(const f16x8*)&sF[0][rA][uo];
            f16x8 ah1 = *(const f16x8*)&sF[0][rA + 32][uo];
            f16x8 al0 = *(const f16x8*)&sF[1][rA][uo];
            f16x8 al1 = *(const f16x8*)&sF[1][rA + 32][uo];
            f16x8 bh0 = *(const f16x8*)&sW[0][rB][uo];
            f16x8 bh1 = *(const f16x8*)&sW[0][rB + 32][uo];
            f16x8 bl0 = *(const f16x8*)&sW[1][rB][uo];
            f16x8 bl1 = *(const f16x8*)&sW[1][rB + 32][uo];
            acc00 = __builtin_amdgcn_mfma_f32_32x32x16_f16(al0, bh0, acc00, 0, 0, 0);
            acc00 = __builtin_amdgcn_mfma_f32_32x32x16_f16(ah0, bl0, acc00, 0, 0, 0);
            acc00 = __builtin_amdgcn_mfma_f32_32x32x16_f16(ah0, bh0, acc00, 0, 0, 0);
            acc01 = __builtin_amdgcn_mfma_f32_32x32x16_f16(al0, bh1, acc01, 0, 0, 0);
            acc01 = __builtin_amdgcn_mfma_f32_32x32x16_f16(ah0, bl1, acc01, 0, 0, 0);
            acc01 = __builtin_amdgcn_mfma_f32_32x32x16_f16(ah0, bh1, acc01, 0, 0, 0);
            acc10 = __builtin_amdgcn_mfma_f32_32x32x16_f16(al1, bh0, acc10, 0, 0, 0);
            acc10 = __builtin_amdgcn_mfma_f32_32x32x16_f16(ah1, bl0, acc10, 0, 0, 0);
            acc10 = __builtin_amdgcn_mfma_f32_32x32x16_f16(ah1, bh0, acc10, 0, 0, 0);
            acc11 = __builtin_amdgcn_mfma_f32_32x32x16_f16(al1, bh1, acc11, 0, 0, 0);
            acc11 = __builtin_amdgcn_mfma_f32_32x32x16_f16(ah1, bl1, acc11, 0, 0, 0);
            acc11 = __builtin_amdgcn_mfma_f32_32x32x16_f16(ah1, bh1, acc11, 0, 0, 0);
        }
    }

    // epilogue: cb + cbh + fp64 chunk norms. C-layout: col=lane&31 (B side),
    // row=(r&3)+8*(r>>2)+4*q (A side).
    #define EPI_A(AIDX, ACC0, ACC1) {                                             \
        int rbase = n0 + wn * 64 + (AIDX) * 32 + 4 * q;                           \
        double ps[16];                                                            \
        _Pragma("unroll")                                                         \
        for (int r = 0; r < 16; ++r) {                                            \
            int nr = rbase + (r & 3) + 8 * (r >> 2);                              \
            int col0 = c0 + wc * 64 + l31;                                        \
            cb[(size_t)nr * K_ + col0] = (ACC0)[r];                               \
            cbh[(size_t)nr * K_ + col0] = f2h((ACC0)[r]);                         \
            cb[(size_t)nr * K_ + col0 + 32] = (ACC1)[r];                          \
            cbh[(size_t)nr * K_ + col0 + 32] = f2h((ACC1)[r]);                    \
            ps[r] = (double)(ACC0)[r] * (ACC0)[r] + (double)(ACC1)[r] * (ACC1)[r];\
        }                                                                         \
        _Pragma("unroll")                                                         \
        for (int r = 0; r < 16; ++r) {                                            \
            double v = ps[r];                                                     \
            _Pragma("unroll")                                                     \
            for (int off = 1; off < 32; off <<= 1) v += __shfl_xor(v, off, 32);   \
            if (l31 == 0) {                                                       \
                int nr = rbase + (r & 3) + 8 * (r >> 2);                          \
                c2part[(size_t)nr * 4 + (c0 >> 6) + wc] = v;                      \
            }                                                                     \
        }                                                                         \
    }
    EPI_A(0, acc00, acc01);
    EPI_A(1, acc10, acc11);
    #undef EPI_A
}

// ---------------------------------------------------------------------------
// C: fp16 MFMA distance scan (R10 structure, measured 90us). Prologue derives
// c2s from c2part and blockIdx.x==0 materializes c2d. t2i = packed (score|idx).
__device__ __forceinline__ void ld_lds16(const void* g, void* l) {
    __builtin_amdgcn_global_load_lds((const __attribute__((address_space(1))) void*)g,
                                     (__attribute__((address_space(3))) void*)l, 16, 0, 0);
}

#define INS(M1, M2, U) { u32 t_ = min(M1, U); u32 h_ = max(M1, U); M1 = t_; M2 = min(M2, h_); }

#define SCORE16(ACC, M1, M2, CGBASE, C2B) do {                                    \
    u32 ib_ = (u32)(code0 + (CGBASE));                                            \
    _Pragma("unroll")                                                             \
    for (int h = 0; h < 4; ++h) {                                                 \
        float4 cv = *(const float4*)&(C2B)[(CGBASE) + 8 * h];                     \
        u32 u0 = (((u32)fmaf(-8192.f, (ACC)[4*h+0], cv.x)) << 13) + ib_ + 8*h + 0; \
        u32 u1 = (((u32)fmaf(-8192.f, (ACC)[4*h+1], cv.y)) << 13) + ib_ + 8*h + 1; \
        u32 u2 = (((u32)fmaf(-8192.f, (ACC)[4*h+2], cv.z)) << 13) + ib_ + 8*h + 2; \
        u32 u3 = (((u32)fmaf(-8192.f, (ACC)[4*h+3], cv.w)) << 13) + ib_ + 8*h + 3; \
        INS(M1, M2, u0); INS(M1, M2, u1); INS(M1, M2, u2); INS(M1, M2, u3);       \
    }                                                                             \
} while (0)

#define WAITVM(N) { asm volatile("s_waitcnt vmcnt(" #N ")" ::: "memory"); \
                    __builtin_amdgcn_s_barrier();                          \
                    __builtin_amdgcn_sched_barrier(0); }

__global__ __launch_bounds__(256, 2) void k_scan_mfma(
        const u16* __restrict__ zh, const u16* __restrict__ cbh,
        const double* __restrict__ c2part, double* __restrict__ c2d,
        int* __restrict__ t2i) {
    __shared__ __align__(16) u16 sA[4][8192];    // 4-step ring, 64KB total
    __shared__ __align__(16) float c2s[2048];    // whole split's pre-scaled c2 (8KB)

    int r0    = blockIdx.x * 128;
    int split = blockIdx.y;
    int tid  = threadIdx.x;
    int wave = tid >> 6, lane = tid & 63;
    int l31 = lane & 31, q = lane >> 5;
    int ra = ((wave & 1) << 6) + l31;            // A row base (codes)

    const u16* zp = zh + (size_t)(r0 + ((wave >> 1) << 6) + l31) * K_ + q * 8;
    f16x8 zr0[16], zr1[16];
    #pragma unroll
    for (int t = 0; t < 16; ++t) {
        zr0[t] = *(const f16x8*)&zp[t * 16];
        zr1[t] = *(const f16x8*)&zp[32 * K_ + t * 16];
    }

    size_t ga[4]; u32 la[4];
    #pragma unroll
    for (int it = 0; it < 4; ++it) {
        int S = (it * 4 + wave) * 64 + lane;
        int row = S >> 3, u = S & 7;
        ga[it] = (size_t)row * K_ + (u ^ (row & 7)) * 8;
        la[it] = (u32)(it * 4 + wave) * 512;
    }

    u32 m1a = 0xFFFFFFFFu, m2a = 0xFFFFFFFFu;
    u32 m1b = 0xFFFFFFFFu, m2b = 0xFFFFFFFFu;

    const u16* cb0 = cbh + (size_t)split * CPS * K_;

    auto STAGE = [&](int s) {
        const u16* Ab = cb0 + (size_t)(s >> 2) * (128 * K_) + (s & 3) * 64;
        u16* d = &sA[s & 3][0];
        #pragma unroll
        for (int it = 0; it < 4; ++it) ld_lds16(Ab + ga[it], d + la[it]);
    };

    f32x16 acc0 = (f32x16){}, acc1 = (f32x16){}, acc2 = (f32x16){}, acc3 = (f32x16){};

    auto COMPUTE = [&](int ct, int kb) {
        const u16* sAb = &sA[kb][0];
        __builtin_amdgcn_s_setprio(1);
        #pragma unroll
        for (int ks = 0; ks < 4; ++ks) {
            u32 u8 = (u32)(((ks * 2 + q) ^ (l31 & 7)) * 8);
            f16x8 af0 = *(const f16x8*)&sAb[(u32)ra * 64 + u8];
            f16x8 af1 = *(const f16x8*)&sAb[(u32)ra * 64 + 2048 + u8];
            acc0 = __builtin_amdgcn_mfma_f32_32x32x16_f16(af0, zr0[kb * 4 + ks], acc0, 0, 0, 0);
            acc1 = __builtin_amdgcn_mfma_f32_32x32x16_f16(af1, zr0[kb * 4 + ks], acc1, 0, 0, 0);
            acc2 = __builtin_amdgcn_mfma_f32_32x32x16_f16(af0, zr1[kb * 4 + ks], acc2, 0, 0, 0);
            acc3 = __builtin_amdgcn_mfma_f32_32x32x16_f16(af1, zr1[kb * 4 + ks], acc3, 0, 0, 0);
        }
        __builtin_amdgcn_s_setprio(0);
        if (kb == 3) {
            int code0 = split * CPS + ct * 128;
            const float* C2B = &c2s[ct * 128];
            int cga = ((wave & 1) << 6) + (q << 2);
            int cgb = cga + 32;
            SCORE16(acc0, m1a, m2a, cga, C2B);
            SCORE16(acc1, m1a, m2a, cgb, C2B);
            SCORE16(acc2, m1b, m2b, cga, C2B);
            SCORE16(acc3, m1b, m2b, cgb, C2B);
            acc0 = (f32x16){}; acc1 = (f32x16){}; acc2 = (f32x16){}; acc3 = (f32x16){};
        }
    };

    // prologue: c2s from c2part + c2d materialization (block x==0); stage 0,1
    {
        const double* cp = c2part + (size_t)split * CPS * 4;
        #pragma unroll
        for (int r = 0; r < 8; ++r) {
            int row = tid * 8 + r;
            const double* pr = cp + (size_t)row * 4;
            double s = (pr[0] + pr[1]) + (pr[2] + pr[3]);
            c2s[row] = (float)(s * 4096.0 + 262144.0);
            if (blockIdx.x == 0) c2d[split * CPS + row] = s;
        }
    }
    STAGE(0); STAGE(1);
    __syncthreads();
    __builtin_amdgcn_sched_barrier(0);

    for (int ct = 0; ct < 15; ++ct) {
        #pragma unroll
        for (int kb = 0; kb < 4; ++kb) {
            STAGE(ct * 4 + kb + 2);
            WAITVM(8);
            COMPUTE(ct, kb);
        }
    }
    STAGE(62); WAITVM(8); COMPUTE(15, 0);
    STAGE(63); WAITVM(8); COMPUTE(15, 1);
    WAITVM(4);            COMPUTE(15, 2);
    WAITVM(0);            COMPUTE(15, 3);

    {
        u32 o1 = __shfl_xor(m1a, 32, 64), o2 = __shfl_xor(m2a, 32, 64);
        u32 h = max(m1a, o1); m1a = min(m1a, o1); m2a = min(min(m2a, o2), h);
        o1 = __shfl_xor(m1b, 32, 64); o2 = __shfl_xor(m2b, 32, 64);
        h = max(m1b, o1); m1b = min(m1b, o1); m2b = min(min(m2b, o2), h);
    }
    u32* mbuf = (u32*)&sA[0][0];
    if (q == 0) {
        int base = ((wave * 2 + 0) * 32 + l31) * 2;
        mbuf[base] = m1a; mbuf[base + 1] = m2a;
        base = ((wave * 2 + 1) * 32 + l31) * 2;
        mbuf[base] = m1b; mbuf[base + 1] = m2b;
    }
    __syncthreads();
    if (tid < 128) {
        int zr = tid, wp = zr >> 6, zg = (zr >> 5) & 1, l = zr & 31;
        int iA = (((wp * 2 + 0) * 2 + zg) * 32 + l) * 2;
        int iB = (((wp * 2 + 1) * 2 + zg) * 32 + l) * 2;
        u32 a1 = mbuf[iA], a2 = mbuf[iA + 1];
        u32 b1 = mbuf[iB], b2 = mbuf[iB + 1];
        u32 h  = max(a1, b1), f1 = min(a1, b1);
        u32 f2 = min(min(a2, b2), h);
        size_t o = ((size_t)split * N_ + (r0 + zr)) * 2;
        t2i[o] = (int)f1;          // PACKED (score|idx)
        t2i[o + 1] = (int)f2;
    }
}

// ---------------------------------------------------------------------------
// D: fp64 rescore with packed-skip (R9/R10 version). Loss via atomicAdd.
__global__ __launch_bounds__(256) void k_finalize(
        const float* __restrict__ zf, const float* __restrict__ cb,
        const double* __restrict__ c2d, const u32* __restrict__ t2i,
        float* __restrict__ out) {
    __shared__ int   bidx[16];
    __shared__ float wsum[4];
    __shared__ float tile[16][260];
    int n0 = blockIdx.x * 16;
    int tid = threadIdx.x;
    int wv = tid >> 6, lane = tid & 63;
    int h = lane >> 5, l5 = lane & 31;
    const u32 W = 160u << 13;

    for (int rr = 0; rr < 4; ++rr) {
        int n = n0 + wv * 4 + rr;
        u32 pk[4];
        u32 b1 = 0xFFFFFFFFu, b2 = 0xFFFFFFFFu;
        #pragma unroll
        for (int p = 0; p < 4; ++p) {
            u32 pa = t2i[((size_t)p * N_ + n) * 2 + 0];
            u32 pb = t2i[((size_t)p * N_ + n) * 2 + 1];
            pk[p] = h ? pb : pa;
            INS(b1, b2, pa); INS(b1, b2, pb);
        }

        int bi;
        if (b2 - b1 >= W) {
            bi = (int)(b1 & 0x1FFFu);
        } else {
            const float* zp = zf + (size_t)n * K_;
            float4 za = *(const float4*)&zp[l5 * 4];
            float4 zb = *(const float4*)&zp[l5 * 4 + 128];
            int cid[4];
            #pragma unroll
            for (int p = 0; p < 4; ++p) cid[p] = (int)(pk[p] & 0x1FFFu);
            double c2p[4];
            #pragma unroll
            for (int p = 0; p < 4; ++p) c2p[p] = c2d[cid[p]];
            float4 cva = *(const float4*)&cb[(size_t)cid[0] * K_ + l5 * 4];
            float4 cvb = *(const float4*)&cb[(size_t)cid[0] * K_ + l5 * 4 + 128];

            double bs = 1e300; bi = 0x7fffffff;
            #pragma unroll
            for (int p = 0; p < 4; ++p) {
                float4 ca = cva, cbv = cvb;
                if (p < 3) {
                    cva = *(const float4*)&cb[(size_t)cid[p + 1] * K_ + l5 * 4];
                    cvb = *(const float4*)&cb[(size_t)cid[p + 1] * K_ + l5 * 4 + 128];
                }
                double acc = (double)za.x * ca.x + (double)za.y * ca.y
                           + (double)za.z * ca.z + (double)za.w * ca.w
                           + (double)zb.x * cbv.x + (double)zb.y * cbv.y
                           + (double)zb.z * cbv.z + (double)zb.w * cbv.w;
                #pragma unroll
                for (int off = 1; off < 32; off <<= 1) acc += __shfl_xor(acc, off, 32);
                double sc = c2p[p] - 2.0 * acc;
                int    ci = cid[p];
                double so = __shfl_xor(sc, 32, 64);
                int    io = __shfl_xor(ci, 32, 64);
                double s0 = h ? so : sc;  int i0 = h ? io : ci;
                double s1 = h ? sc : so;  int i1 = h ? ci : io;
                if (s0 < bs || (s0 == bs && i0 < bi)) { bs = s0; bi = i0; }
                if (s1 < bs || (s1 == bs && i1 < bi)) { bs = s1; bi = i1; }
            }
        }
        if (lane == 0) {
            bidx[wv * 4 + rr] = bi;
            out[(size_t)NZQ + 1 + n] = (float)bi;
        }
    }
    __syncthreads();

    float accl = 0.f;
    for (int l = 0; l < 16; ++l) {
        int n = n0 + l;
        int bi = bidx[l];
        float zq = cb[(size_t)bi * K_ + tid];
        float d  = zf[(size_t)n * K_ + tid] - zq;
        accl += d * d;
        tile[l][tid] = zq;
    }
    #pragma unroll
    for (int off = 32; off; off >>= 1) accl += __shfl_down(accl, off, 64);
    if ((tid & 63) == 0) wsum[tid >> 6] = accl;
    __syncthreads();
    if (tid == 0)
        atomicAdd(out + NZQ, (wsum[0] + wsum[1] + wsum[2] + wsum[3]) * (1.25f / (float)NZQ));
    int b = n0 >> 10, hw0 = n0 & 1023;
    #pragma unroll
    for (int g = 0; g < 4; ++g) {
        float4 v = make_float4(tile[g * 4 + 0][tid], tile[g * 4 + 1][tid],
                               tile[g * 4 + 2][tid], tile[g * 4 + 3][tid]);
        *(float4*)&out[((size_t)b * C_ + tid) * HW_ + hw0 + g * 4] = v;
    }
}

// ---------------------------------------------------------------------------
extern "C" void kernel_launch(void* const* d_in, const int* in_sizes, int n_in,
                              void* d_out, int out_size, void* d_ws, size_t ws_size,
                              hipStream_t stream) {
    const float* z  = (const float*)d_in[0];
    const float* fc = (const float*)d_in[1];
    const float* wt = (const float*)d_in[2];
    float* out = (float*)d_out;

    float* ws = (float*)d_ws;
    const size_t OFF_ZF   = 0;                                   // N*K f
    const size_t OFF_CB   = OFF_ZF + (size_t)N_ * K_;            // NE*K f
    const size_t OFF_C2P  = OFF_CB + (size_t)NE_ * K_;           // NE*4 d (8 f each)
    const size_t OFF_C2D  = OFF_C2P + (size_t)NE_ * 8;           // NE d (2 f each)
    const size_t OFF_T2I  = OFF_C2D + (size_t)NE_ * 2;           // NSPLIT*N*2 i
    const size_t OFF_ZH   = OFF_T2I + (size_t)NSPLIT * N_ * 2;   // fp16 N*K
    const size_t OFF_CBH  = OFF_ZH + (size_t)N_ * K_ / 2;        // fp16 NE*K

    float*  zf     = ws + OFF_ZF;
    float*  cb     = ws + OFF_CB;
    double* c2part = (double*)(ws + OFF_C2P);
    double* c2d    = (double*)(ws + OFF_C2D);
    int*    t2i    = (int*)(ws + OFF_T2I);
    u16*    zh     = (u16*)(ws + OFF_ZH);
    u16*    cbh    = (u16*)(ws + OFF_CBH);

    k_pre<<<4224, 256, 0, stream>>>(z, fc, wt, zf, zh, cb, cbh, c2part);
    k_scan_mfma<<<dim3(N_ / 128, NSPLIT), 256, 0, stream>>>(zh, cbh, c2part, c2d, t2i);
    k_finalize<<<N_ / 16, 256, 0, stream>>>(zf, cb, c2d, (const u32*)t2i, out);
}